// Round 1
// baseline (1097.463 us; speedup 1.0000x reference)
//
#include <hip/hip_runtime.h>

// ---------------------------------------------------------------------------
// Net_65798898975283: 2x GraphConv (add-aggr) + 3-layer MLP head + log_softmax
// N=20000 nodes, E=320000 edges, D_in=256, dims 256->128->64->128->64->10
//
// Restructure: segment_sum(x[src]) @ W_rel == segment_sum((x@W_rel)[src]),
// so we project first, then scatter-add the projected (narrower) features
// directly into the (x @ W_root + b) buffer.
// ---------------------------------------------------------------------------

#define NNODES 20000
#define NEDGES 320000

// Generic small tiled fp32 GEMM: C[M,N] = op(A)[M,K] @ B[K,N] (+bias)(+relu)
// Requires N % 16 == 0 and K % 16 == 0 (true for all uses: N in {64,128}, K in {64,128,256}).
template<bool RELU_IN, bool BIAS, bool RELU_OUT>
__global__ void gemm16(const float* __restrict__ A, const float* __restrict__ B,
                       const float* __restrict__ bias, float* __restrict__ C,
                       int M, int N, int K) {
    __shared__ float As[16][17];
    __shared__ float Bs[16][17];
    const int tx = threadIdx.x, ty = threadIdx.y;
    const int row = blockIdx.y * 16 + ty;
    const int col = blockIdx.x * 16 + tx;
    float acc = 0.f;
    for (int k0 = 0; k0 < K; k0 += 16) {
        float a = (row < M) ? A[(size_t)row * K + k0 + tx] : 0.f;
        if (RELU_IN) a = fmaxf(a, 0.f);
        As[ty][tx] = a;
        Bs[ty][tx] = B[(size_t)(k0 + ty) * N + col];
        __syncthreads();
        #pragma unroll
        for (int k = 0; k < 16; ++k)
            acc += As[ty][k] * Bs[k][tx];
        __syncthreads();
    }
    if (row < M) {
        if (BIAS) acc += bias[col];
        if (RELU_OUT) acc = fmaxf(acc, 0.f);
        C[(size_t)row * N + col] = acc;
    }
}

// Scatter-add: out[dst[e], :] += feat[src[e], :], D = 4 << dv_shift floats.
// One thread handles 4 consecutive floats (float4 read, 4 scalar atomics).
__global__ void scatter_add4(const float* __restrict__ feat, const int* __restrict__ src,
                             const int* __restrict__ dst, float* __restrict__ out,
                             int n_edges, int dv_shift) {
    const unsigned Dv = 1u << dv_shift;  // D/4
    unsigned idx = blockIdx.x * blockDim.x + threadIdx.x;
    unsigned total = (unsigned)n_edges << dv_shift;
    if (idx >= total) return;
    unsigned e = idx >> dv_shift;
    unsigned c = idx & (Dv - 1);
    int s = src[e];
    int d = dst[e];
    const float4 v = reinterpret_cast<const float4*>(feat)[((size_t)s << dv_shift) + c];
    float* o = out + (((size_t)d << dv_shift) + c) * 4;
    atomicAdd(o + 0, v.x);
    atomicAdd(o + 1, v.y);
    atomicAdd(o + 2, v.z);
    atomicAdd(o + 3, v.w);
}

// Head: logits = H4[node, 0:64] @ W[64,10] + b; out = log_softmax(logits)
__global__ void head_kernel(const float* __restrict__ H4, const float* __restrict__ W,
                            const float* __restrict__ b, float* __restrict__ out,
                            int n_nodes) {
    __shared__ float Ws[640];
    __shared__ float bs[10];
    for (int i = threadIdx.x; i < 640; i += blockDim.x) Ws[i] = W[i];
    if (threadIdx.x < 10) bs[threadIdx.x] = b[threadIdx.x];
    __syncthreads();
    int node = blockIdx.x * blockDim.x + threadIdx.x;
    if (node >= n_nodes) return;
    const float* h = H4 + (size_t)node * 64;
    float logit[10];
    #pragma unroll
    for (int c = 0; c < 10; ++c) logit[c] = bs[c];
    #pragma unroll
    for (int k = 0; k < 64; ++k) {
        float hv = h[k];
        #pragma unroll
        for (int c = 0; c < 10; ++c) logit[c] += hv * Ws[k * 10 + c];
    }
    float m = logit[0];
    #pragma unroll
    for (int c = 1; c < 10; ++c) m = fmaxf(m, logit[c]);
    float s = 0.f;
    #pragma unroll
    for (int c = 0; c < 10; ++c) s += expf(logit[c] - m);
    float lse = m + logf(s);
    float* o = out + (size_t)node * 10;
    #pragma unroll
    for (int c = 0; c < 10; ++c) o[c] = logit[c] - lse;
}

extern "C" void kernel_launch(void* const* d_in, const int* in_sizes, int n_in,
                              void* d_out, int out_size, void* d_ws, size_t ws_size,
                              hipStream_t stream) {
    const float* x       = (const float*)d_in[0];
    const int*   edge    = (const int*)d_in[1];
    const int*   src     = edge;            // edge_index[0]
    const int*   dst     = edge + NEDGES;   // edge_index[1]
    const float* W1_rel  = (const float*)d_in[2];
    const float* W1_root = (const float*)d_in[3];
    const float* b1      = (const float*)d_in[4];
    const float* W2_rel  = (const float*)d_in[5];
    const float* W2_root = (const float*)d_in[6];
    const float* b2      = (const float*)d_in[7];
    const float* lin1_w  = (const float*)d_in[8];
    const float* lin1_b  = (const float*)d_in[9];
    const float* lin2_w  = (const float*)d_in[10];
    const float* lin2_b  = (const float*)d_in[11];
    const float* lin3_w  = (const float*)d_in[12];
    const float* lin3_b  = (const float*)d_in[13];
    float* out = (float*)d_out;
    float* ws  = (float*)d_ws;

    const int M = NNODES;
    // workspace layout (floats), regions reused stream-ordered:
    float* XR  = ws;                    // [M,128] x @ W1_rel
    float* H1  = ws + (size_t)M * 128;  // [M,128] conv1 out (pre/post relu-in-gemm)
    float* H2R = ws;                    // [M,64]  relu(H1) @ W2_rel   (reuses XR)
    float* H2  = ws + (size_t)M * 64;   // [M,64]  conv2 out          (reuses XR hi-half)
    float* H3  = ws + (size_t)M * 128;  // [M,128] mlp1 out           (reuses H1)
    float* H4  = ws;                    // [M,64]  mlp2 out           (reuses H2R)

    dim3 blk(16, 16);
    dim3 g128(128 / 16, (M + 15) / 16);
    dim3 g64(64 / 16, (M + 15) / 16);

    // ---- conv1: H1 = segsum((x@W1_rel)[src]->dst) + x@W1_root + b1 ----
    gemm16<false, false, false><<<g128, blk, 0, stream>>>(x, W1_rel, nullptr, XR, M, 128, 256);
    gemm16<false, true,  false><<<g128, blk, 0, stream>>>(x, W1_root, b1, H1, M, 128, 256);
    {
        unsigned total = (unsigned)NEDGES * 32u;  // D=128 -> 32 float4/edge
        scatter_add4<<<(total + 255) / 256, 256, 0, stream>>>(XR, src, dst, H1, NEDGES, 5);
    }

    // ---- conv2 (input = relu(H1), no relu on output) ----
    gemm16<true, false, false><<<g64, blk, 0, stream>>>(H1, W2_rel, nullptr, H2R, M, 64, 128);
    gemm16<true, true,  false><<<g64, blk, 0, stream>>>(H1, W2_root, b2, H2, M, 64, 128);
    {
        unsigned total = (unsigned)NEDGES * 16u;  // D=64 -> 16 float4/edge
        scatter_add4<<<(total + 255) / 256, 256, 0, stream>>>(H2R, src, dst, H2, NEDGES, 4);
    }

    // ---- MLP head ----
    gemm16<false, true, true><<<g128, blk, 0, stream>>>(H2, lin1_w, lin1_b, H3, M, 128, 64);
    gemm16<false, true, true><<<g64,  blk, 0, stream>>>(H3, lin2_w, lin2_b, H4, M, 64, 128);
    head_kernel<<<(M + 255) / 256, 256, 0, stream>>>(H4, lin3_w, lin3_b, out, M);
}

// Round 2
// 279.820 us; speedup vs baseline: 3.9220x; 3.9220x over previous
//
#include <hip/hip_runtime.h>

// ---------------------------------------------------------------------------
// Net_65798898975283: 2x GraphConv (add-aggr) + 3-layer MLP head + log_softmax
// N=20000 nodes, E=320000 edges, D_in=256, dims 256->128->64->128->64->10
//
// R1: replace atomic scatter (was 810us, atomic-throughput-bound, VALUBusy
// 0.8%) with device-built CSR + per-node gather. Upgrade GEMM to 64x64 tile,
// 4x4 register blocking.
// ---------------------------------------------------------------------------

#define NNODES 20000
#define NEDGES 320000
#define SCAN_THREADS 1024
#define SCAN_CHUNK 20   // 1024*20 = 20480 >= 20000

// ---------------- CSR build ----------------
__global__ void hist_kernel(const int* __restrict__ dst, int* __restrict__ cnt, int E) {
    int e = blockIdx.x * blockDim.x + threadIdx.x;
    if (e < E) atomicAdd(&cnt[dst[e]], 1);
}

// Single-block exclusive scan of cnt[0..n-1] -> ofs[0..n], n <= 20480.
__global__ void scan_kernel(const int* __restrict__ cnt, int* __restrict__ ofs, int n) {
    __shared__ int part[SCAN_THREADS];
    const int t = threadIdx.x;
    const int base = t * SCAN_CHUNK;
    int loc[SCAN_CHUNK];
    int s = 0;
    #pragma unroll
    for (int i = 0; i < SCAN_CHUNK; ++i) {
        int v = (base + i < n) ? cnt[base + i] : 0;
        loc[i] = s;
        s += v;
    }
    part[t] = s;
    __syncthreads();
    #pragma unroll
    for (int off = 1; off < SCAN_THREADS; off <<= 1) {
        int v = (t >= off) ? part[t - off] : 0;
        __syncthreads();
        part[t] += v;
        __syncthreads();
    }
    const int pre = (t > 0) ? part[t - 1] : 0;
    #pragma unroll
    for (int i = 0; i < SCAN_CHUNK; ++i)
        if (base + i < n) ofs[base + i] = pre + loc[i];
    if (t == 0) ofs[n] = part[SCAN_THREADS - 1];
}

__global__ void fill_kernel(const int* __restrict__ src, const int* __restrict__ dst,
                            const int* __restrict__ ofs, int* __restrict__ cur,
                            int* __restrict__ nbr, int E) {
    int e = blockIdx.x * blockDim.x + threadIdx.x;
    if (e >= E) return;
    int d = dst[e];
    int p = atomicAdd(&cur[d], 1);
    nbr[ofs[d] + p] = src[e];
}

// ---------------- gather-aggregate: out[i,:] += sum_{s in nbr(i)} feat[s,:] ----
template<int D>
__global__ void gather_add(const float* __restrict__ feat, const int* __restrict__ ofs,
                           const int* __restrict__ nbr, float* __restrict__ out) {
    const int node = blockIdx.x;
    const int c = threadIdx.x;
    const int beg = ofs[node], end = ofs[node + 1];
    float acc = out[(size_t)node * D + c];
    for (int j = beg; j < end; ++j) {
        int s = nbr[j];
        acc += feat[(size_t)s * D + c];
    }
    out[(size_t)node * D + c] = acc;
}

// ---------------- GEMM: C[M,N] = op(A)[M,K] @ B[K,N] (+bias)(+relu) ----------
// 64x64 tile, 256 threads, 4x4 per-thread. Requires N%64==0, K%16==0.
template<bool RELU_IN, bool BIAS, bool RELU_OUT>
__global__ void gemm64(const float* __restrict__ A, const float* __restrict__ B,
                       const float* __restrict__ bias, float* __restrict__ C,
                       int M, int N, int K) {
    __shared__ float As[16][68];  // [k][m], padded
    __shared__ float Bs[16][68];  // [k][n], padded
    const int tid = threadIdx.x;
    const int tx = tid & 15, ty = tid >> 4;
    const int bm = blockIdx.y * 64, bn = blockIdx.x * 64;
    float acc[4][4] = {};
    for (int k0 = 0; k0 < K; k0 += 16) {
        #pragma unroll
        for (int i = tid; i < 64 * 16; i += 256) {
            int r = i >> 4, c = i & 15;
            float a = (bm + r < M) ? A[(size_t)(bm + r) * K + k0 + c] : 0.f;
            if (RELU_IN) a = fmaxf(a, 0.f);
            As[c][r] = a;
        }
        #pragma unroll
        for (int i = tid; i < 16 * 64; i += 256) {
            int kk = i >> 6, c = i & 63;
            Bs[kk][c] = B[(size_t)(k0 + kk) * N + bn + c];
        }
        __syncthreads();
        #pragma unroll
        for (int kk = 0; kk < 16; ++kk) {
            float av[4], bv[4];
            #pragma unroll
            for (int i = 0; i < 4; ++i) av[i] = As[kk][ty * 4 + i];
            #pragma unroll
            for (int j = 0; j < 4; ++j) bv[j] = Bs[kk][tx * 4 + j];
            #pragma unroll
            for (int i = 0; i < 4; ++i)
                #pragma unroll
                for (int j = 0; j < 4; ++j) acc[i][j] += av[i] * bv[j];
        }
        __syncthreads();
    }
    #pragma unroll
    for (int i = 0; i < 4; ++i) {
        int r = bm + ty * 4 + i;
        if (r >= M) continue;
        #pragma unroll
        for (int j = 0; j < 4; ++j) {
            int cl = bn + tx * 4 + j;
            float v = acc[i][j];
            if (BIAS) v += bias[cl];
            if (RELU_OUT) v = fmaxf(v, 0.f);
            C[(size_t)r * N + cl] = v;
        }
    }
}

// ---------------- head: log_softmax(H4 @ W[64,10] + b) ----------------------
__global__ void head_kernel(const float* __restrict__ H4, const float* __restrict__ W,
                            const float* __restrict__ b, float* __restrict__ out,
                            int n_nodes) {
    __shared__ float Ws[640];
    __shared__ float bs[10];
    for (int i = threadIdx.x; i < 640; i += blockDim.x) Ws[i] = W[i];
    if (threadIdx.x < 10) bs[threadIdx.x] = b[threadIdx.x];
    __syncthreads();
    int node = blockIdx.x * blockDim.x + threadIdx.x;
    if (node >= n_nodes) return;
    const float* h = H4 + (size_t)node * 64;
    float logit[10];
    #pragma unroll
    for (int c = 0; c < 10; ++c) logit[c] = bs[c];
    #pragma unroll
    for (int k = 0; k < 64; ++k) {
        float hv = h[k];
        #pragma unroll
        for (int c = 0; c < 10; ++c) logit[c] += hv * Ws[k * 10 + c];
    }
    float m = logit[0];
    #pragma unroll
    for (int c = 1; c < 10; ++c) m = fmaxf(m, logit[c]);
    float s = 0.f;
    #pragma unroll
    for (int c = 0; c < 10; ++c) s += expf(logit[c] - m);
    float lse = m + logf(s);
    float* o = out + (size_t)node * 10;
    #pragma unroll
    for (int c = 0; c < 10; ++c) o[c] = logit[c] - lse;
}

extern "C" void kernel_launch(void* const* d_in, const int* in_sizes, int n_in,
                              void* d_out, int out_size, void* d_ws, size_t ws_size,
                              hipStream_t stream) {
    const float* x       = (const float*)d_in[0];
    const int*   edge    = (const int*)d_in[1];
    const int*   src     = edge;            // edge_index[0]
    const int*   dst     = edge + NEDGES;   // edge_index[1]
    const float* W1_rel  = (const float*)d_in[2];
    const float* W1_root = (const float*)d_in[3];
    const float* b1      = (const float*)d_in[4];
    const float* W2_rel  = (const float*)d_in[5];
    const float* W2_root = (const float*)d_in[6];
    const float* b2      = (const float*)d_in[7];
    const float* lin1_w  = (const float*)d_in[8];
    const float* lin1_b  = (const float*)d_in[9];
    const float* lin2_w  = (const float*)d_in[10];
    const float* lin2_b  = (const float*)d_in[11];
    const float* lin3_w  = (const float*)d_in[12];
    const float* lin3_b  = (const float*)d_in[13];
    float* out = (float*)d_out;
    float* ws  = (float*)d_ws;

    const int M = NNODES;
    // float workspace: two [M,128] regions, reused stream-ordered
    float* F0 = ws;                     // XR / {H2R, H2} / H4
    float* F1 = ws + (size_t)M * 128;   // H1 / H3
    // int workspace after the float regions
    int* iws = (int*)(ws + (size_t)2 * M * 128);
    int* ofs = iws;                 // [N+1]
    int* cur = iws + (NNODES + 1);  // [N]
    int* nbr = cur + NNODES;        // [E]

    float* XR  = F0;
    float* H1  = F1;
    float* H2R = F0;
    float* H2  = F0 + (size_t)M * 64;
    float* H3  = F1;
    float* H4  = F0;

    dim3 blk(256);
    dim3 g128(128 / 64, (M + 63) / 64);
    dim3 g64(64 / 64, (M + 63) / 64);
    const int eblocks = (NEDGES + 255) / 256;

    // ---- CSR build (dst-keyed, stores src) ----
    hipMemsetAsync(cur, 0, NNODES * sizeof(int), stream);
    hist_kernel<<<eblocks, 256, 0, stream>>>(dst, cur, NEDGES);
    scan_kernel<<<1, SCAN_THREADS, 0, stream>>>(cur, ofs, NNODES);
    hipMemsetAsync(cur, 0, NNODES * sizeof(int), stream);
    fill_kernel<<<eblocks, 256, 0, stream>>>(src, dst, ofs, cur, nbr, NEDGES);

    // ---- conv1: H1 = gather(x@W1_rel) + x@W1_root + b1 ----
    gemm64<false, false, false><<<g128, blk, 0, stream>>>(x, W1_rel, nullptr, XR, M, 128, 256);
    gemm64<false, true,  false><<<g128, blk, 0, stream>>>(x, W1_root, b1, H1, M, 128, 256);
    gather_add<128><<<NNODES, 128, 0, stream>>>(XR, ofs, nbr, H1);

    // ---- conv2 (input = relu(H1), no relu on output) ----
    gemm64<true, false, false><<<g64, blk, 0, stream>>>(H1, W2_rel, nullptr, H2R, M, 64, 128);
    gemm64<true, true,  false><<<g64, blk, 0, stream>>>(H1, W2_root, b2, H2, M, 64, 128);
    gather_add<64><<<NNODES, 64, 0, stream>>>(H2R, ofs, nbr, H2);

    // ---- MLP head ----
    gemm64<false, true, true><<<g128, blk, 0, stream>>>(H2, lin1_w, lin1_b, H3, M, 128, 64);
    gemm64<false, true, true><<<g64,  blk, 0, stream>>>(H3, lin2_w, lin2_b, H4, M, 64, 128);
    head_kernel<<<(M + 255) / 256, 256, 0, stream>>>(H4, lin3_w, lin3_b, out, M);
}

// Round 3
// 205.533 us; speedup vs baseline: 5.3396x; 1.3614x over previous
//
#include <hip/hip_runtime.h>

// ---------------------------------------------------------------------------
// Net_65798898975283: 2x GraphConv (add-aggr) + 3-layer MLP head + log_softmax
// N=20000 nodes, E=320000 edges, dims 256->128->64->128->64->10
//
// R2: GEMMs -> bf16 MFMA (16x16x32, fp32 accum). Weights pretransposed to
// bf16 [N][K] once per launch. Conv rel/root GEMM pairs fused. All activations
// live in one [M][256] stride-256 fp32 region:
//   conv1 out: cols 0..127 = XR (rel), 128..255 = H1 (root+b1); gather1: XR->H1
//   conv2 out: cols 0..63 = H2R, 64..127 = H2 (root+b2);        gather2: H2R->H2
//   mlp1 out:  cols 128..255 = H3 (H1 dead)
//   mlp2 out:  cols 0..63    = H4 (H2R dead)
// ---------------------------------------------------------------------------

#define NNODES 20000
#define NEDGES 320000
#define SCAN_THREADS 1024
#define SCAN_CHUNK 20   // 1024*20 = 20480 >= 20000

typedef __attribute__((ext_vector_type(8))) short bf16x8;
typedef __attribute__((ext_vector_type(4))) float f32x4;

__device__ inline short f2bf(float f) {
    unsigned u = __builtin_bit_cast(unsigned, f);
    u += 0x7FFFu + ((u >> 16) & 1u);   // RNE to bf16 (finite inputs)
    return (short)(u >> 16);
}

// ---------------- weight pretranspose/convert: W[K][N] f32 -> WT[N][K] bf16 --
// WT1: 256 rows(K=256): n<128 W1_rel else W1_root
// WT2: 128 rows(K=128): n<64 W2_rel else W2_root
// WT3: 128 rows(K=64):  lin1_w
// WT4: 64 rows(K=128):  lin2_w
__global__ void wt_transpose(const float* __restrict__ W1r, const float* __restrict__ W1o,
                             const float* __restrict__ W2r, const float* __restrict__ W2o,
                             const float* __restrict__ L1,  const float* __restrict__ L2,
                             short* __restrict__ WT) {
    int idx = blockIdx.x * blockDim.x + threadIdx.x;  // 0 .. 98303
    float v;
    if (idx < 65536) {
        int n = idx >> 8, k = idx & 255;
        v = (n < 128) ? W1r[k * 128 + n] : W1o[k * 128 + (n - 128)];
        WT[idx] = f2bf(v);
    } else if (idx < 65536 + 16384) {
        int i = idx - 65536;
        int n = i >> 7, k = i & 127;
        v = (n < 64) ? W2r[k * 64 + n] : W2o[k * 64 + (n - 64)];
        WT[idx] = f2bf(v);
    } else if (idx < 65536 + 16384 + 8192) {
        int i = idx - (65536 + 16384);
        int n = i >> 6, k = i & 63;     // WT3[n][k] = lin1_w[k][n], [64][128]
        WT[idx] = f2bf(L1[k * 128 + n]);
    } else {
        int i = idx - (65536 + 16384 + 8192);
        int n = i >> 7, k = i & 127;    // WT4[n][k] = lin2_w[k][n], [128][64]
        WT[idx] = f2bf(L2[k * 64 + n]);
    }
}

// ---------------- CSR build ----------------
__global__ void hist_kernel(const int* __restrict__ dst, int* __restrict__ cnt, int E) {
    int e = blockIdx.x * blockDim.x + threadIdx.x;
    if (e < E) atomicAdd(&cnt[dst[e]], 1);
}

__global__ void scan_kernel(const int* __restrict__ cnt, int* __restrict__ ofs, int n) {
    __shared__ int part[SCAN_THREADS];
    const int t = threadIdx.x;
    const int base = t * SCAN_CHUNK;
    int loc[SCAN_CHUNK];
    int s = 0;
    #pragma unroll
    for (int i = 0; i < SCAN_CHUNK; ++i) {
        int v = (base + i < n) ? cnt[base + i] : 0;
        loc[i] = s;
        s += v;
    }
    part[t] = s;
    __syncthreads();
    #pragma unroll
    for (int off = 1; off < SCAN_THREADS; off <<= 1) {
        int v = (t >= off) ? part[t - off] : 0;
        __syncthreads();
        part[t] += v;
        __syncthreads();
    }
    const int pre = (t > 0) ? part[t - 1] : 0;
    #pragma unroll
    for (int i = 0; i < SCAN_CHUNK; ++i)
        if (base + i < n) ofs[base + i] = pre + loc[i];
    if (t == 0) ofs[n] = part[SCAN_THREADS - 1];
}

__global__ void fill_kernel(const int* __restrict__ src, const int* __restrict__ dst,
                            const int* __restrict__ ofs, int* __restrict__ cur,
                            int* __restrict__ nbr, int E) {
    int e = blockIdx.x * blockDim.x + threadIdx.x;
    if (e >= E) return;
    int d = dst[e];
    int p = atomicAdd(&cur[d], 1);
    nbr[ofs[d] + p] = src[e];
}

// ---------------- gather-aggregate (strided): out[i,c] += sum feat[nbr,c] ----
template<int D>
__global__ void gather_add(const float* __restrict__ feat, int ldf,
                           const int* __restrict__ ofs, const int* __restrict__ nbr,
                           float* __restrict__ out, int ldo) {
    const int node = blockIdx.x;
    const int c = threadIdx.x;
    const int beg = ofs[node], end = ofs[node + 1];
    float acc = out[(size_t)node * ldo + c];
    for (int j = beg; j < end; ++j)
        acc += feat[(size_t)nbr[j] * ldf + c];
    out[(size_t)node * ldo + c] = acc;
}

// ---------------- bf16 MFMA GEMM -------------------------------------------
// C[M x Nc] (stride ldc, fp32) = op(A[M x K], stride lda, fp32->bf16) @ BT^T
// BT is [Nc][K] bf16. Tile: BM=128, BN=64, BK=32; 256 threads = 4 waves,
// wave w -> rows [w*32, w*32+32), 2x4 MFMA 16x16x32 tiles.
template<bool RELU_IN, bool BIAS, bool RELU_OUT>
__global__ __launch_bounds__(256)
void gemm_mfma(const float* __restrict__ A, int lda,
               const short* __restrict__ BT,
               const float* __restrict__ bias, int bias_col0,
               float* __restrict__ C, int ldc,
               int M, int K) {
    __shared__ short Asl[128][40];  // row stride 80B -> conflict-friendly
    __shared__ short Bsl[64][40];
    const int tid = threadIdx.x;
    const int bm = blockIdx.y * 128;
    const int bn = blockIdx.x * 64;
    const int wid = tid >> 6, lane = tid & 63;
    const int lr = lane & 15, lg = lane >> 4;
    f32x4 acc[2][4] = {};

    for (int k0 = 0; k0 < K; k0 += 32) {
        // stage A: 128 rows x 32 k, fp32 -> bf16 (optional relu)
        #pragma unroll
        for (int p = 0; p < 4; ++p) {
            int idx = tid + p * 256;          // 0..1023
            int row = idx >> 3;
            int c4 = (idx & 7) * 4;
            int g = bm + row;
            float4 v = make_float4(0.f, 0.f, 0.f, 0.f);
            if (g < M) v = *reinterpret_cast<const float4*>(A + (size_t)g * lda + k0 + c4);
            if (RELU_IN) {
                v.x = fmaxf(v.x, 0.f); v.y = fmaxf(v.y, 0.f);
                v.z = fmaxf(v.z, 0.f); v.w = fmaxf(v.w, 0.f);
            }
            short4 h;
            h.x = f2bf(v.x); h.y = f2bf(v.y); h.z = f2bf(v.z); h.w = f2bf(v.w);
            *reinterpret_cast<short4*>(&Asl[row][c4]) = h;
        }
        // stage B: 64 cols x 32 k, already bf16 [n][k]
        {
            int n = tid >> 2;
            int kc = (tid & 3) * 8;
            float4 raw = *reinterpret_cast<const float4*>(BT + (size_t)(bn + n) * K + k0 + kc);
            *reinterpret_cast<float4*>(&Bsl[n][kc]) = raw;
        }
        __syncthreads();

        bf16x8 a0 = *reinterpret_cast<const bf16x8*>(&Asl[wid * 32 + lr][lg * 8]);
        bf16x8 a1 = *reinterpret_cast<const bf16x8*>(&Asl[wid * 32 + 16 + lr][lg * 8]);
        #pragma unroll
        for (int nt = 0; nt < 4; ++nt) {
            bf16x8 b = *reinterpret_cast<const bf16x8*>(&Bsl[nt * 16 + lr][lg * 8]);
            acc[0][nt] = __builtin_amdgcn_mfma_f32_16x16x32_bf16(a0, b, acc[0][nt], 0, 0, 0);
            acc[1][nt] = __builtin_amdgcn_mfma_f32_16x16x32_bf16(a1, b, acc[1][nt], 0, 0, 0);
        }
        __syncthreads();
    }

    // epilogue: C row = (lane>>4)*4 + reg, col = lane&15  (m89 layout)
    #pragma unroll
    for (int mt = 0; mt < 2; ++mt) {
        #pragma unroll
        for (int r = 0; r < 4; ++r) {
            int row = bm + wid * 32 + mt * 16 + lg * 4 + r;
            if (row >= M) continue;
            #pragma unroll
            for (int nt = 0; nt < 4; ++nt) {
                int col = bn + nt * 16 + lr;
                float v = acc[mt][nt][r];
                if (BIAS && col >= bias_col0) v += bias[col - bias_col0];
                if (RELU_OUT) v = fmaxf(v, 0.f);
                C[(size_t)row * ldc + col] = v;
            }
        }
    }
}

// ---------------- head: log_softmax(H4 @ W[64,10] + b) ----------------------
__global__ void head_kernel(const float* __restrict__ H4, int ldh,
                            const float* __restrict__ W,
                            const float* __restrict__ b, float* __restrict__ out,
                            int n_nodes) {
    __shared__ float Ws[640];
    __shared__ float bs[10];
    for (int i = threadIdx.x; i < 640; i += blockDim.x) Ws[i] = W[i];
    if (threadIdx.x < 10) bs[threadIdx.x] = b[threadIdx.x];
    __syncthreads();
    int node = blockIdx.x * blockDim.x + threadIdx.x;
    if (node >= n_nodes) return;
    const float* h = H4 + (size_t)node * ldh;
    float logit[10];
    #pragma unroll
    for (int c = 0; c < 10; ++c) logit[c] = bs[c];
    #pragma unroll
    for (int k = 0; k < 64; ++k) {
        float hv = h[k];
        #pragma unroll
        for (int c = 0; c < 10; ++c) logit[c] += hv * Ws[k * 10 + c];
    }
    float m = logit[0];
    #pragma unroll
    for (int c = 1; c < 10; ++c) m = fmaxf(m, logit[c]);
    float s = 0.f;
    #pragma unroll
    for (int c = 0; c < 10; ++c) s += expf(logit[c] - m);
    float lse = m + logf(s);
    float* o = out + (size_t)node * 10;
    #pragma unroll
    for (int c = 0; c < 10; ++c) o[c] = logit[c] - lse;
}

extern "C" void kernel_launch(void* const* d_in, const int* in_sizes, int n_in,
                              void* d_out, int out_size, void* d_ws, size_t ws_size,
                              hipStream_t stream) {
    const float* x       = (const float*)d_in[0];
    const int*   edge    = (const int*)d_in[1];
    const int*   src     = edge;            // edge_index[0]
    const int*   dst     = edge + NEDGES;   // edge_index[1]
    const float* W1_rel  = (const float*)d_in[2];
    const float* W1_root = (const float*)d_in[3];
    const float* b1      = (const float*)d_in[4];
    const float* W2_rel  = (const float*)d_in[5];
    const float* W2_root = (const float*)d_in[6];
    const float* b2      = (const float*)d_in[7];
    const float* lin1_w  = (const float*)d_in[8];
    const float* lin1_b  = (const float*)d_in[9];
    const float* lin2_w  = (const float*)d_in[10];
    const float* lin2_b  = (const float*)d_in[11];
    const float* lin3_w  = (const float*)d_in[12];
    const float* lin3_b  = (const float*)d_in[13];
    float* out = (float*)d_out;
    float* ws  = (float*)d_ws;

    const int M = NNODES;
    // ws layout: [M*256 floats C1] [ints: ofs(N+1), cur(N), nbr(E)] [shorts WT]
    float* C1 = ws;
    int* iws = (int*)(ws + (size_t)M * 256);
    int* ofs = iws;                 // [N+1]
    int* cur = iws + (NNODES + 1);  // [N]
    int* nbr = cur + NNODES;        // [E]
    short* WT  = (short*)(nbr + NEDGES);
    short* WT1 = WT;                 // 256 x 256
    short* WT2 = WT1 + 65536;        // 128 x 128
    short* WT3 = WT2 + 16384;        // 128 x 64
    short* WT4 = WT3 + 8192;         // 64 x 128

    const int eblocks = (NEDGES + 255) / 256;

    // ---- weights -> bf16 [N][K] ----
    wt_transpose<<<384, 256, 0, stream>>>(W1_rel, W1_root, W2_rel, W2_root,
                                          lin1_w, lin2_w, WT);

    // ---- CSR build (dst-keyed, stores src) ----
    hipMemsetAsync(cur, 0, NNODES * sizeof(int), stream);
    hist_kernel<<<eblocks, 256, 0, stream>>>(dst, cur, NEDGES);
    scan_kernel<<<1, SCAN_THREADS, 0, stream>>>(cur, ofs, NNODES);
    hipMemsetAsync(cur, 0, NNODES * sizeof(int), stream);
    fill_kernel<<<eblocks, 256, 0, stream>>>(src, dst, ofs, cur, nbr, NEDGES);

    const int mb = (M + 127) / 128;  // 157

    // ---- conv1 (fused rel|root): C1[:,0:128]=x@W1_rel, C1[:,128:256]=x@W1_root+b1
    gemm_mfma<false, true, false><<<dim3(4, mb), 256, 0, stream>>>(
        x, 256, WT1, b1, 128, C1, 256, M, 256);
    gather_add<128><<<NNODES, 128, 0, stream>>>(C1, 256, ofs, nbr, C1 + 128, 256);

    // ---- conv2 (A = relu(H1)): C1[:,0:64]=H2R, C1[:,64:128]=H2(root+b2)
    gemm_mfma<true, true, false><<<dim3(2, mb), 256, 0, stream>>>(
        C1 + 128, 256, WT2, b2, 64, C1, 256, M, 128);
    gather_add<64><<<NNODES, 64, 0, stream>>>(C1, 256, ofs, nbr, C1 + 64, 256);

    // ---- mlp1: H3 = relu(H2 @ lin1_w + b) -> C1[:,128:256]
    gemm_mfma<false, true, true><<<dim3(2, mb), 256, 0, stream>>>(
        C1 + 64, 256, WT3, lin1_b, 0, C1 + 128, 256, M, 64);

    // ---- mlp2: H4 = relu(H3 @ lin2_w + b) -> C1[:,0:64]
    gemm_mfma<false, true, true><<<dim3(1, mb), 256, 0, stream>>>(
        C1 + 128, 256, WT4, lin2_b, 0, C1, 256, M, 128);

    // ---- head ----
    head_kernel<<<(M + 255) / 256, 256, 0, stream>>>(C1, 256, lin3_w, lin3_b, out, M);
}

// Round 4
// 158.837 us; speedup vs baseline: 6.9094x; 1.2940x over previous
//
#include <hip/hip_runtime.h>

// ---------------------------------------------------------------------------
// Net_65798898975283: 2x GraphConv (add-aggr) + 3-layer MLP head + log_softmax
// N=20000 nodes, E=320000 edges, dims 256->128->64->128->64->10
//
// R3: all activations stored bf16 (they pass through bf16 at MFMA staging
// anyway). Gathers read bf16x8 (16B/lane), accumulate fp32, write bf16.
// relu(conv1) folded into gather1 write. CSR build: fused memset, fused
// wt_transpose+hist dispatch, shfl-based scan.
// Buffers:
//   C1A bf16 [M][256]: cols 0:128 = x@W1_rel, 128:256 = x@W1_root+b1
//   H1  bf16 [M][128]: relu(gather(C1A.rel) + C1A.root)
//   C2A bf16 [M][128]: cols 0:64 = H1@W2_rel, 64:128 = H1@W2_root+b2
//   H2  bf16 [M][64]:  gather(C2A.rel) + C2A.root   (no relu)
//   H3  bf16 [M][128]: relu(H2@lin1_w+b)
//   H4  bf16 [M][64]:  relu(H3@lin2_w+b)
// ---------------------------------------------------------------------------

#define NNODES 20000
#define NEDGES 320000

typedef __attribute__((ext_vector_type(8))) short bf16x8;
typedef __attribute__((ext_vector_type(4))) float f32x4;

__device__ inline short f2bf(float f) {
    unsigned u = __builtin_bit_cast(unsigned, f);
    u += 0x7FFFu + ((u >> 16) & 1u);   // RNE (finite inputs)
    return (short)(u >> 16);
}
__device__ inline float bf2f(short h) {
    unsigned u = ((unsigned)(unsigned short)h) << 16;
    return __builtin_bit_cast(float, u);
}

// ---------------- prep: weight transpose->bf16  +  dst histogram -----------
// blocks [0,384): WT build; blocks [384, 384+1250): histogram of dst.
__global__ void prep_kernel(const float* __restrict__ W1r, const float* __restrict__ W1o,
                            const float* __restrict__ W2r, const float* __restrict__ W2o,
                            const float* __restrict__ L1,  const float* __restrict__ L2,
                            short* __restrict__ WT,
                            const int* __restrict__ dst, int* __restrict__ cnt) {
    const int b = blockIdx.x;
    if (b < 384) {
        int idx = b * 256 + threadIdx.x;   // 0..98303
        float v;
        if (idx < 65536) {                       // WT1 [256][256]
            int n = idx >> 8, k = idx & 255;
            v = (n < 128) ? W1r[k * 128 + n] : W1o[k * 128 + (n - 128)];
        } else if (idx < 65536 + 16384) {        // WT2 [128][128]
            int i = idx - 65536;
            int n = i >> 7, k = i & 127;
            v = (n < 64) ? W2r[k * 64 + n] : W2o[k * 64 + (n - 64)];
        } else if (idx < 65536 + 16384 + 8192) { // WT3 [128][64]
            int i = idx - (65536 + 16384);
            int n = i >> 6, k = i & 63;
            v = L1[k * 128 + n];
        } else {                                 // WT4 [64][128]
            int i = idx - (65536 + 16384 + 8192);
            int n = i >> 7, k = i & 127;
            v = L2[k * 64 + n];
        }
        WT[idx] = f2bf(v);
    } else {
        int e = (b - 384) * 256 + threadIdx.x;   // exactly covers NEDGES
        atomicAdd(&cnt[dst[e]], 1);
    }
}

// ---------------- scan: exclusive prefix over cnt[0..n-1] -> ofs[0..n] ------
#define SCAN_CHUNK 20   // 1024*20 = 20480 >= 20000
__global__ void scan_kernel(const int* __restrict__ cnt, int* __restrict__ ofs, int n) {
    __shared__ int wsum[16];
    const int t = threadIdx.x;
    const int lane = t & 63, wid = t >> 6;
    const int base = t * SCAN_CHUNK;
    int loc[SCAN_CHUNK];
    int s = 0;
    #pragma unroll
    for (int i = 0; i < SCAN_CHUNK; ++i) {
        int v = (base + i < n) ? cnt[base + i] : 0;
        loc[i] = s;
        s += v;
    }
    // inclusive wave scan of s
    int v = s;
    #pragma unroll
    for (int off = 1; off < 64; off <<= 1) {
        int u = __shfl_up(v, off);
        if (lane >= off) v += u;
    }
    if (lane == 63) wsum[wid] = v;
    __syncthreads();
    if (t < 16) {
        int w = wsum[t];
        #pragma unroll
        for (int off = 1; off < 16; off <<= 1) {
            int u = __shfl_up(w, off);
            if (t >= off) w += u;
        }
        wsum[t] = w;  // inclusive over waves
    }
    __syncthreads();
    const int wpre = (wid > 0) ? wsum[wid - 1] : 0;
    const int excl = wpre + (v - s);
    #pragma unroll
    for (int i = 0; i < SCAN_CHUNK; ++i)
        if (base + i < n) ofs[base + i] = excl + loc[i];
    if (t == 1023) ofs[n] = wpre + v;
}

__global__ void fill_kernel(const int* __restrict__ src, const int* __restrict__ dst,
                            const int* __restrict__ ofs, int* __restrict__ cur,
                            int* __restrict__ nbr) {
    int e = blockIdx.x * blockDim.x + threadIdx.x;   // exactly NEDGES threads
    int d = dst[e];
    int p = atomicAdd(&cur[d], 1);
    nbr[ofs[d] + p] = src[e];
}

// ---------------- gather: out[i,:] = opt_relu(init[i,:] + sum feat[nbr,:]) --
// bf16 in / fp32 accum / bf16 out. GPN = D/8 lanes per node, 16B loads.
template<int D, int GPN, bool RELU>
__global__ void gather_bf16(const short* __restrict__ rel, int ldr,
                            const short* __restrict__ init, int ldi,
                            const int* __restrict__ ofs, const int* __restrict__ nbr,
                            short* __restrict__ outp, int ldo) {
    const int tid = threadIdx.x;
    const int node = blockIdx.x * (256 / GPN) + tid / GPN;
    const int c8 = (tid % GPN) * 8;
    float acc[8];
    bf16x8 iv = *reinterpret_cast<const bf16x8*>(init + (size_t)node * ldi + c8);
    #pragma unroll
    for (int i = 0; i < 8; ++i) acc[i] = bf2f(iv[i]);
    const int beg = ofs[node], end = ofs[node + 1];
    for (int j = beg; j < end; ++j) {
        int s = nbr[j];
        bf16x8 vv = *reinterpret_cast<const bf16x8*>(rel + (size_t)s * ldr + c8);
        #pragma unroll
        for (int i = 0; i < 8; ++i) acc[i] += bf2f(vv[i]);
    }
    bf16x8 o;
    #pragma unroll
    for (int i = 0; i < 8; ++i) {
        float vo = RELU ? fmaxf(acc[i], 0.f) : acc[i];
        o[i] = f2bf(vo);
    }
    *reinterpret_cast<bf16x8*>(outp + (size_t)node * ldo + c8) = o;
}

// ---------------- bf16 MFMA GEMM, bf16 C out --------------------------------
// C[M x Nc] bf16 (stride ldc) = A[M x K] @ BT^T  (+bias on cols>=bias_col0)
// A: fp32 (cvt at staging) if !ABF16, else bf16 (straight copy).
// Tile BM=128, BN=64, BK=32; 256 threads = 4 waves; wave -> 32 rows, 2x4 MFMA.
template<bool ABF16, bool RELU_OUT>
__global__ __launch_bounds__(256)
void gemm_mfma(const void* __restrict__ Av, int lda,
               const short* __restrict__ BT,
               const float* __restrict__ bias, int bias_col0,
               short* __restrict__ C, int ldc,
               int M, int K) {
    __shared__ short Asl[128][40];
    __shared__ short Bsl[64][40];
    const int tid = threadIdx.x;
    const int bm = blockIdx.y * 128;
    const int bn = blockIdx.x * 64;
    const int wid = tid >> 6, lane = tid & 63;
    const int lr = lane & 15, lg = lane >> 4;
    f32x4 acc[2][4] = {};

    for (int k0 = 0; k0 < K; k0 += 32) {
        if (ABF16) {
            const short* A = (const short*)Av;
            #pragma unroll
            for (int p = 0; p < 2; ++p) {
                int idx = tid + p * 256;        // 0..511
                int row = idx >> 2;
                int cc = (idx & 3) * 8;
                int g = bm + row;
                bf16x8 v = {};
                if (g < M) v = *reinterpret_cast<const bf16x8*>(A + (size_t)g * lda + k0 + cc);
                *reinterpret_cast<bf16x8*>(&Asl[row][cc]) = v;
            }
        } else {
            const float* A = (const float*)Av;
            #pragma unroll
            for (int p = 0; p < 4; ++p) {
                int idx = tid + p * 256;        // 0..1023
                int row = idx >> 3;
                int c4 = (idx & 7) * 4;
                int g = bm + row;
                float4 v = make_float4(0.f, 0.f, 0.f, 0.f);
                if (g < M) v = *reinterpret_cast<const float4*>(A + (size_t)g * lda + k0 + c4);
                short4 h;
                h.x = f2bf(v.x); h.y = f2bf(v.y); h.z = f2bf(v.z); h.w = f2bf(v.w);
                *reinterpret_cast<short4*>(&Asl[row][c4]) = h;
            }
        }
        {
            int n = tid >> 2;
            int kc = (tid & 3) * 8;
            float4 raw = *reinterpret_cast<const float4*>(BT + (size_t)(bn + n) * K + k0 + kc);
            *reinterpret_cast<float4*>(&Bsl[n][kc]) = raw;
        }
        __syncthreads();

        bf16x8 a0 = *reinterpret_cast<const bf16x8*>(&Asl[wid * 32 + lr][lg * 8]);
        bf16x8 a1 = *reinterpret_cast<const bf16x8*>(&Asl[wid * 32 + 16 + lr][lg * 8]);
        #pragma unroll
        for (int nt = 0; nt < 4; ++nt) {
            bf16x8 b = *reinterpret_cast<const bf16x8*>(&Bsl[nt * 16 + lr][lg * 8]);
            acc[0][nt] = __builtin_amdgcn_mfma_f32_16x16x32_bf16(a0, b, acc[0][nt], 0, 0, 0);
            acc[1][nt] = __builtin_amdgcn_mfma_f32_16x16x32_bf16(a1, b, acc[1][nt], 0, 0, 0);
        }
        __syncthreads();
    }

    // epilogue: row = lg*4 + r, col = lr (m89 layout), bf16 store
    #pragma unroll
    for (int mt = 0; mt < 2; ++mt) {
        #pragma unroll
        for (int r = 0; r < 4; ++r) {
            int row = bm + wid * 32 + mt * 16 + lg * 4 + r;
            if (row >= M) continue;
            #pragma unroll
            for (int nt = 0; nt < 4; ++nt) {
                int col = bn + nt * 16 + lr;
                float v = acc[mt][nt][r];
                if (col >= bias_col0) v += bias[col - bias_col0];
                if (RELU_OUT) v = fmaxf(v, 0.f);
                C[(size_t)row * ldc + col] = f2bf(v);
            }
        }
    }
}

// ---------------- head: log_softmax(H4 @ W[64,10] + b), H4 bf16 -------------
__global__ void head_kernel(const short* __restrict__ H4, int ldh,
                            const float* __restrict__ W,
                            const float* __restrict__ b, float* __restrict__ out,
                            int n_nodes) {
    __shared__ float Ws[640];
    __shared__ float bs[10];
    for (int i = threadIdx.x; i < 640; i += blockDim.x) Ws[i] = W[i];
    if (threadIdx.x < 10) bs[threadIdx.x] = b[threadIdx.x];
    __syncthreads();
    int node = blockIdx.x * blockDim.x + threadIdx.x;
    if (node >= n_nodes) return;
    const short* h = H4 + (size_t)node * ldh;
    float logit[10];
    #pragma unroll
    for (int c = 0; c < 10; ++c) logit[c] = bs[c];
    #pragma unroll
    for (int k8 = 0; k8 < 8; ++k8) {
        bf16x8 hv8 = *reinterpret_cast<const bf16x8*>(h + k8 * 8);
        #pragma unroll
        for (int i = 0; i < 8; ++i) {
            float hv = bf2f(hv8[i]);
            #pragma unroll
            for (int c = 0; c < 10; ++c) logit[c] += hv * Ws[(k8 * 8 + i) * 10 + c];
        }
    }
    float m = logit[0];
    #pragma unroll
    for (int c = 1; c < 10; ++c) m = fmaxf(m, logit[c]);
    float s = 0.f;
    #pragma unroll
    for (int c = 0; c < 10; ++c) s += expf(logit[c] - m);
    float lse = m + logf(s);
    float* o = out + (size_t)node * 10;
    #pragma unroll
    for (int c = 0; c < 10; ++c) o[c] = logit[c] - lse;
}

extern "C" void kernel_launch(void* const* d_in, const int* in_sizes, int n_in,
                              void* d_out, int out_size, void* d_ws, size_t ws_size,
                              hipStream_t stream) {
    const float* x       = (const float*)d_in[0];
    const int*   edge    = (const int*)d_in[1];
    const int*   src     = edge;            // edge_index[0]
    const int*   dst     = edge + NEDGES;   // edge_index[1]
    const float* W1_rel  = (const float*)d_in[2];
    const float* W1_root = (const float*)d_in[3];
    const float* b1      = (const float*)d_in[4];
    const float* W2_rel  = (const float*)d_in[5];
    const float* W2_root = (const float*)d_in[6];
    const float* b2      = (const float*)d_in[7];
    const float* lin1_w  = (const float*)d_in[8];
    const float* lin1_b  = (const float*)d_in[9];
    const float* lin2_w  = (const float*)d_in[10];
    const float* lin2_b  = (const float*)d_in[11];
    const float* lin3_w  = (const float*)d_in[12];
    const float* lin3_b  = (const float*)d_in[13];
    float* out = (float*)d_out;

    const int M = NNODES;
    char* p = (char*)d_ws;
    auto alloc = [&](size_t bytes) { char* r = p; p += (bytes + 63) & ~63ull; return r; };
    short* WT  = (short*)alloc(98304 * 2);
    short* WT1 = WT;                 // [256][256]
    short* WT2 = WT1 + 65536;        // [128][128]
    short* WT3 = WT2 + 16384;        // [128][64]
    short* WT4 = WT3 + 8192;         // [64][128]
    short* C1A = (short*)alloc((size_t)M * 256 * 2);
    short* H1  = (short*)alloc((size_t)M * 128 * 2);
    short* C2A = (short*)alloc((size_t)M * 128 * 2);
    short* H2  = (short*)alloc((size_t)M * 64 * 2);
    short* H3  = (short*)alloc((size_t)M * 128 * 2);
    short* H4  = (short*)alloc((size_t)M * 64 * 2);
    int* ofs = (int*)alloc((NNODES + 1) * 4);
    int* cur = (int*)alloc(2 * NNODES * 4);   // [0:N) hist, [N:2N) fill cursor
    int* nbr = (int*)alloc(NEDGES * 4);

    // ---- CSR + weights ----
    hipMemsetAsync(cur, 0, 2 * NNODES * sizeof(int), stream);
    prep_kernel<<<384 + NEDGES / 256, 256, 0, stream>>>(
        W1_rel, W1_root, W2_rel, W2_root, lin1_w, lin2_w, WT, dst, cur);
    scan_kernel<<<1, 1024, 0, stream>>>(cur, ofs, NNODES);
    fill_kernel<<<NEDGES / 256, 256, 0, stream>>>(src, dst, ofs, cur + NNODES, nbr);

    const int mb = (M + 127) / 128;  // 157

    // ---- conv1: C1A = [x@W1_rel | x@W1_root + b1] ----
    gemm_mfma<false, false><<<dim3(4, mb), 256, 0, stream>>>(
        x, 256, WT1, b1, 128, C1A, 256, M, 256);
    gather_bf16<128, 16, true><<<NNODES / 16, 256, 0, stream>>>(
        C1A, 256, C1A + 128, 256, ofs, nbr, H1, 128);

    // ---- conv2: C2A = [H1@W2_rel | H1@W2_root + b2] (no relu out) ----
    gemm_mfma<true, false><<<dim3(2, mb), 256, 0, stream>>>(
        H1, 128, WT2, b2, 64, C2A, 128, M, 128);
    gather_bf16<64, 8, false><<<NNODES / 32, 256, 0, stream>>>(
        C2A, 128, C2A + 64, 128, ofs, nbr, H2, 64);

    // ---- mlp ----
    gemm_mfma<true, true><<<dim3(2, mb), 256, 0, stream>>>(
        H2, 64, WT3, lin1_b, 0, H3, 128, M, 64);
    gemm_mfma<true, true><<<dim3(1, mb), 256, 0, stream>>>(
        H3, 128, WT4, lin2_b, 0, H4, 64, M, 128);

    // ---- head ----
    head_kernel<<<(M + 255) / 256, 256, 0, stream>>>(H4, 64, lin3_w, lin3_b, out, M);
}